// Round 4
// baseline (242.689 us; speedup 1.0000x reference)
//
#include <hip/hip_runtime.h>
#include <stdint.h>

// Problem constants (from reference)
#define B_   128
#define C_   3
#define H_   256
#define W_   256
#define CH_  64          // cutout height = int(256*0.25)
#define CW_  64          // cutout width
#define HW_  (H_ * W_)   // 65536 elements per plane
#define PROB_ 0.9f
#define NBLK_ 512        // 4 blocks per image
// factor = 1 - K + 2*K*u = 0.8 + 0.4*u  for K = 0.2 (BRI/CON/SAT)

// ---------- bf16 helpers (raw ushort bit handling, fp32 math) ----------
__device__ __forceinline__ float bf_lo(uint32_t u) {
    union { uint32_t u; float f; } c; c.u = u << 16; return c.f;
}
__device__ __forceinline__ float bf_hi(uint32_t u) {
    union { uint32_t u; float f; } c; c.u = u & 0xFFFF0000u; return c.f;
}
__device__ __forceinline__ float bf_val(uint16_t v) {
    union { uint32_t u; float f; } c; c.u = ((uint32_t)v) << 16; return c.f;
}
__device__ __forceinline__ uint16_t f2bf(float f) {
    union { float f; uint32_t u; } c; c.f = f;
    uint32_t u = c.u;
    return (uint16_t)((u + 0x7FFFu + ((u >> 16) & 1u)) >> 16);
}
__device__ __forceinline__ void unpack8(uint4 v, float e[8]) {
    e[0] = bf_lo(v.x); e[1] = bf_hi(v.x);
    e[2] = bf_lo(v.y); e[3] = bf_hi(v.y);
    e[4] = bf_lo(v.z); e[5] = bf_hi(v.z);
    e[6] = bf_lo(v.w); e[7] = bf_hi(v.w);
}

// Scalar decode honoring detected layout: bf16[b] vs fp32[b]
__device__ __forceinline__ float scal(const void* p, int b, int is_bf16) {
    if (is_bf16) return bf_val(((const uint16_t*)p)[b]);
    return ((const float*)p)[b];
}

// Wave-0 dtype sniffer: view first 256 B as 128 bf16. bf16 uniform[0,1) data
// -> all in [0,1). fp32 data -> low-half words are random mantissa bits.
// Call with threadIdx.x < 64 only.
__device__ __forceinline__ bool sniff_bf16_01(const uint16_t* u, int lane) {
    bool ok = true;
    #pragma unroll
    for (int k = 0; k < 2; ++k) {
        float v = bf_val(u[lane + 64 * k]);
        ok = ok && (v >= 0.0f) && (v < 1.0f);   // NaN -> false
    }
    unsigned long long m = __ballot(ok);
    return m == ~0ull;
}

// ---------- Fused single-pass kernel with device-scope spin barrier ----------
// 512 blocks x 256 threads, 4 blocks per image (64-row slabs), 2 blocks/CU
// (launch_bounds caps VGPR at 256; reg cache 96 + ~60 working). All 512
// blocks co-resident on 256 CUs, so the spin barrier completes; if residency
// assumptions ever break, the bailout path recomputes means locally
// (correct, just slower) instead of hanging.
//
// grid.sync()/cooperative launch is NOT used: round-3 evidence shows it
// degrades to a no-op under the harness's graph capture (apply-images got
// ws-poison garbage means, absmax 468). The barrier counter is zeroed each
// iteration by a stream-ordered hipMemsetAsync (ws is re-poisoned by the
// harness every iteration, so no cross-launch state survives anyway).
__global__ __launch_bounds__(256, 2) void fused_aug_kernel(
    const void* __restrict__ img,
    const void* __restrict__ apply_u,
    const void* __restrict__ flip_u,
    const void* __restrict__ bri_u,
    const void* __restrict__ con_u,
    const void* __restrict__ sat_u,
    const int*  __restrict__ top_idx,
    const int*  __restrict__ left_idx,
    float*      __restrict__ partials,
    uint32_t*   __restrict__ counter,
    void*       __restrict__ out)
{
    __shared__ int   s_flags;
    __shared__ float wsum[4][3];
    __shared__ float s_p[12];
    __shared__ int   s_ok;

    if (threadIdx.x < 64) {
        const bool ib = sniff_bf16_01((const uint16_t*)img, threadIdx.x);
        const bool sb = sniff_bf16_01((const uint16_t*)apply_u, threadIdx.x);
        if (threadIdx.x == 0) s_flags = (ib ? 1 : 0) | (sb ? 2 : 0);
    }
    __syncthreads();
    const int imgbf = s_flags & 1;
    const int scbf  = (s_flags >> 1) & 1;

    const int b   = blockIdx.x >> 2;   // image
    const int q   = blockIdx.x & 3;    // 64-row slab within image
    const int tid = threadIdx.x;

    const bool apply = scal(apply_u, b, scbf) < PROB_;
    const bool flip  = apply && (scal(flip_u, b, scbf) < 0.5f);

    // ---- Phase 1: load (from flipped source when flipping -- per-plane sum
    // is flip-invariant), accumulate channel sums, keep raw words in regs.
    uint4 cache[3][8];                 // bf16 path: 24 uint4 = 192 px
    float csum[3] = {0.0f, 0.0f, 0.0f};

    #pragma unroll
    for (int c = 0; c < 3; ++c) {
        #pragma unroll
        for (int k = 0; k < 8; ++k) {
            const int i  = tid + 256 * k;          // vec idx in slab [0,2048)
            const int h  = q * 64 + (i >> 5);      // 32 vecs per row
            const int w0 = (i & 31) << 3;
            const int sw = flip ? (W_ - 8 - w0) : w0;
            const size_t off = (size_t)(b * 3 + c) * HW_ + (size_t)h * W_ + sw;
            if (imgbf) {
                const uint4 v = *(const uint4*)((const uint16_t*)img + off);
                cache[c][k] = v;
                float e[8]; unpack8(v, e);
                csum[c] += ((e[0] + e[1]) + (e[2] + e[3])) + ((e[4] + e[5]) + (e[6] + e[7]));
            } else {
                const float* ip = (const float*)img + off;
                const float4 v0 = *(const float4*)(ip);
                const float4 v1 = *(const float4*)(ip + 4);
                csum[c] += ((v0.x + v0.y) + (v0.z + v0.w)) + ((v1.x + v1.y) + (v1.z + v1.w));
            }
        }
    }

    // block reduction of the 3 channel sums
    #pragma unroll
    for (int c = 0; c < 3; ++c) {
        float s = csum[c];
        #pragma unroll
        for (int off = 32; off > 0; off >>= 1) s += __shfl_down(s, off, 64);
        if ((tid & 63) == 0) wsum[tid >> 6][c] = s;
    }
    __syncthreads();
    if (tid < 3) {
        const float v = (wsum[0][tid] + wsum[1][tid]) + (wsum[2][tid] + wsum[3][tid]);
        // device-scope release store: visible across XCDs (non-coherent L2s)
        __hip_atomic_store(&partials[blockIdx.x * 3 + tid], v,
                           __ATOMIC_RELEASE, __HIP_MEMORY_SCOPE_AGENT);
    }
    __syncthreads();                   // partial stores issued before arrive

    // ---- Device-scope spin barrier (counter pre-zeroed via memset) ----
    if (tid == 0) {
        __hip_atomic_fetch_add(counter, 1u, __ATOMIC_ACQ_REL, __HIP_MEMORY_SCOPE_AGENT);
        int ok = 0;
        for (int it = 0; it < 20000; ++it) {
            if (__hip_atomic_load(counter, __ATOMIC_ACQUIRE, __HIP_MEMORY_SCOPE_AGENT)
                >= (uint32_t)NBLK_) { ok = 1; break; }
            __builtin_amdgcn_s_sleep(2);
        }
        s_ok = ok;
    }
    __syncthreads();

    // ---- per-plane raw means ----
    float mraw[3];
    if (s_ok) {
        if (tid < 12)
            s_p[tid] = __hip_atomic_load(&partials[b * 12 + tid],
                                         __ATOMIC_ACQUIRE, __HIP_MEMORY_SCOPE_AGENT);
        __syncthreads();
        #pragma unroll
        for (int c = 0; c < 3; ++c)
            mraw[c] = ((s_p[0 + c] + s_p[3 + c]) + (s_p[6 + c] + s_p[9 + c]))
                      * (1.0f / (float)HW_);
    } else {
        // Bailout insurance: recompute full-plane means locally (L3-hot).
        // Correct regardless of other blocks' progress.
        #pragma unroll
        for (int c = 0; c < 3; ++c) {
            float s = 0.0f;
            if (imgbf) {
                const uint4* p = (const uint4*)((const uint16_t*)img + (size_t)(b * 3 + c) * HW_);
                for (int i = tid; i < HW_ / 8; i += 256) {
                    float e[8]; unpack8(p[i], e);
                    s += ((e[0] + e[1]) + (e[2] + e[3])) + ((e[4] + e[5]) + (e[6] + e[7]));
                }
            } else {
                const float4* p = (const float4*)((const float*)img + (size_t)(b * 3 + c) * HW_);
                for (int i = tid; i < HW_ / 4; i += 256) {
                    float4 v = p[i];
                    s += (v.x + v.y) + (v.z + v.w);
                }
            }
            #pragma unroll
            for (int off = 32; off > 0; off >>= 1) s += __shfl_down(s, off, 64);
            if ((tid & 63) == 0) wsum[tid >> 6][c] = s;
        }
        __syncthreads();
        #pragma unroll
        for (int c = 0; c < 3; ++c)
            mraw[c] = ((wsum[0][c] + wsum[1][c]) + (wsum[2][c] + wsum[3][c]))
                      * (1.0f / (float)HW_);
    }

    // ---- Phase 2 ----
    if (!apply) {
        // bit-exact passthrough (cache holds unflipped raw words)
        #pragma unroll
        for (int c = 0; c < 3; ++c) {
            #pragma unroll
            for (int k = 0; k < 8; ++k) {
                const int i  = tid + 256 * k;
                const int h  = q * 64 + (i >> 5);
                const int w0 = (i & 31) << 3;
                const size_t off = (size_t)(b * 3 + c) * HW_ + (size_t)h * W_ + w0;
                if (imgbf) {
                    *(uint4*)((uint16_t*)out + off) = cache[c][k];
                } else {
                    const float* ip = (const float*)img + off;
                    float*       op = (float*)out + off;
                    *(float4*)(op)     = *(const float4*)(ip);
                    *(float4*)(op + 4) = *(const float4*)(ip + 4);
                }
            }
        }
        return;
    }

    const float fb = 0.8f + 0.4f * scal(bri_u, b, scbf);
    const float fc = 0.8f + 0.4f * scal(con_u, b, scbf);
    const float fs = 0.8f + 0.4f * scal(sat_u, b, scbf);
    const int   tt = top_idx[b];
    const int   ll = left_idx[b];

    #pragma unroll
    for (int k = 0; k < 8; ++k) {
        const int i  = tid + 256 * k;
        const int h  = q * 64 + (i >> 5);
        const int w0 = (i & 31) << 3;
        const bool row_in = (h >= tt) && (h < tt + CH_);

        float x[3][8];
        #pragma unroll
        for (int c = 0; c < 3; ++c) {
            float e[8];
            if (imgbf) {
                unpack8(cache[c][k], e);
            } else {
                const int sw = flip ? (W_ - 8 - w0) : w0;
                const float* ip = (const float*)img
                                  + (size_t)(b * 3 + c) * HW_ + (size_t)h * W_ + sw;
                const float4 v0 = *(const float4*)(ip);
                const float4 v1 = *(const float4*)(ip + 4);
                e[0] = v0.x; e[1] = v0.y; e[2] = v0.z; e[3] = v0.w;
                e[4] = v1.x; e[5] = v1.y; e[6] = v1.z; e[7] = v1.w;
            }
            // mean after brightness = fb * raw_mean (flip doesn't change the mean)
            const float m = fb * mraw[c];
            #pragma unroll
            for (int j = 0; j < 8; ++j) {
                const float src = flip ? e[7 - j] : e[j];
                x[c][j] = (src * fb - m) * fc + m;   // brightness + contrast
            }
        }

        // saturation (per-pixel channel mean) + cutout
        #pragma unroll
        for (int j = 0; j < 8; ++j) {
            const float gray = (x[0][j] + x[1][j] + x[2][j]) * (1.0f / 3.0f);
            const int   w    = w0 + j;
            const bool inside = row_in && (w >= ll) && (w < ll + CW_);
            #pragma unroll
            for (int c = 0; c < 3; ++c) {
                const float y = (x[c][j] - gray) * fs + gray;
                x[c][j] = inside ? 0.0f : y;
            }
        }

        // pack + store (output dtype follows images dtype)
        #pragma unroll
        for (int c = 0; c < 3; ++c) {
            const size_t off = (size_t)(b * 3 + c) * HW_ + (size_t)h * W_ + w0;
            if (imgbf) {
                uint4 ov;
                ov.x = (uint32_t)f2bf(x[c][0]) | ((uint32_t)f2bf(x[c][1]) << 16);
                ov.y = (uint32_t)f2bf(x[c][2]) | ((uint32_t)f2bf(x[c][3]) << 16);
                ov.z = (uint32_t)f2bf(x[c][4]) | ((uint32_t)f2bf(x[c][5]) << 16);
                ov.w = (uint32_t)f2bf(x[c][6]) | ((uint32_t)f2bf(x[c][7]) << 16);
                *(uint4*)((uint16_t*)out + off) = ov;
            } else {
                float4 v0, v1;
                v0.x = x[c][0]; v0.y = x[c][1]; v0.z = x[c][2]; v0.w = x[c][3];
                v1.x = x[c][4]; v1.y = x[c][5]; v1.z = x[c][6]; v1.w = x[c][7];
                float* op = (float*)out + off;
                *(float4*)(op)     = v0;
                *(float4*)(op + 4) = v1;
            }
        }
    }
}

extern "C" void kernel_launch(void* const* d_in, const int* in_sizes, int n_in,
                              void* d_out, int out_size, void* d_ws, size_t ws_size,
                              hipStream_t stream) {
    const void* img     = d_in[0];
    const void* apply_u = d_in[1];
    const void* flip_u  = d_in[2];
    const void* bri_u   = d_in[3];
    const void* con_u   = d_in[4];
    const void* sat_u   = d_in[5];
    const int*  top_i   = (const int*)d_in[6];
    const int*  left_i  = (const int*)d_in[7];
    float*      partials = (float*)d_ws;                       // 1536 floats
    uint32_t*   counter  = (uint32_t*)((char*)d_ws + 8192);    // barrier counter

    // zero the barrier counter (stream-ordered; capture-legal -- the harness
    // itself enqueues hipMemsetAsync inside the timed capture)
    hipMemsetAsync(counter, 0, sizeof(uint32_t), stream);

    fused_aug_kernel<<<NBLK_, 256, 0, stream>>>(
        img, apply_u, flip_u, bri_u, con_u, sat_u, top_i, left_i,
        partials, counter, d_out);
}

// Round 5
// 207.849 us; speedup vs baseline: 1.1676x; 1.1676x over previous
//
#include <hip/hip_runtime.h>
#include <stdint.h>

// Problem constants (from reference)
#define B_   128
#define C_   3
#define H_   256
#define W_   256
#define CH_  64          // cutout height = int(256*0.25)
#define CW_  64          // cutout width
#define HW_  (H_ * W_)   // 65536 elements per plane
#define NPLANES (B_ * C_)
#define PROB_ 0.9f
// factor = 1 - K + 2*K*u = 0.8 + 0.4*u  for K = 0.2 (BRI/CON/SAT)

// ---------- bf16 helpers (raw ushort bit handling, fp32 math) ----------
__device__ __forceinline__ float bf_lo(uint32_t u) {
    union { uint32_t u; float f; } c; c.u = u << 16; return c.f;
}
__device__ __forceinline__ float bf_hi(uint32_t u) {
    union { uint32_t u; float f; } c; c.u = u & 0xFFFF0000u; return c.f;
}
__device__ __forceinline__ float bf_val(uint16_t v) {
    union { uint32_t u; float f; } c; c.u = ((uint32_t)v) << 16; return c.f;
}
__device__ __forceinline__ uint16_t f2bf(float f) {
    // round-to-nearest-even; values here are finite
    union { float f; uint32_t u; } c; c.f = f;
    uint32_t u = c.u;
    return (uint16_t)((u + 0x7FFFu + ((u >> 16) & 1u)) >> 16);
}
__device__ __forceinline__ void unpack8(uint4 v, float e[8]) {
    e[0] = bf_lo(v.x); e[1] = bf_hi(v.x);
    e[2] = bf_lo(v.y); e[3] = bf_hi(v.y);
    e[4] = bf_lo(v.z); e[5] = bf_hi(v.z);
    e[6] = bf_lo(v.w); e[7] = bf_hi(v.w);
}

// Scalar decode honoring detected layout: bf16[b] vs fp32[b]
__device__ __forceinline__ float scal(const void* p, int b, int is_bf16) {
    if (is_bf16) return bf_val(((const uint16_t*)p)[b]);
    return ((const float*)p)[b];
}

// Wave-0 dtype sniffer: view first 256 B as 128 bf16. bf16 uniform[0,1) data
// -> all in [0,1). fp32 data -> low-half words are random mantissa bits,
// P(all 64 in range) ~ 0.25^64 ~ 1e-39. Call with threadIdx.x < 64 only.
__device__ __forceinline__ bool sniff_bf16_01(const uint16_t* u, int lane) {
    bool ok = true;
    #pragma unroll
    for (int k = 0; k < 2; ++k) {
        float v = bf_val(u[lane + 64 * k]);
        ok = ok && (v >= 0.0f) && (v < 1.0f);   // NaN -> false
    }
    unsigned long long m = __ballot(ok);
    return m == ~0ull;
}

// ---------- Pass 1: per-(b,c) raw spatial mean + dtype sniffers ----------
// 384 blocks, one per plane, 512 threads. HBM-bound (reads full image once);
// measured insensitive to block-count restructuring (r1 vs r2: 207.4 vs 207.7).
__global__ __launch_bounds__(512) void plane_mean_kernel(
    const void* __restrict__ img, const void* __restrict__ apply_u,
    float* __restrict__ means, int* __restrict__ flags)
{
    __shared__ int s_imgbf;
    if (threadIdx.x < 64) {
        const bool ib = sniff_bf16_01((const uint16_t*)img, threadIdx.x);
        bool sb = false;
        if (blockIdx.x == 0) sb = sniff_bf16_01((const uint16_t*)apply_u, threadIdx.x);
        if (threadIdx.x == 0) {
            s_imgbf = ib ? 1 : 0;
            if (blockIdx.x == 0) { flags[0] = ib ? 1 : 0; flags[1] = sb ? 1 : 0; }
        }
    }
    __syncthreads();
    const int imgbf = s_imgbf;
    const int plane = blockIdx.x;

    float s = 0.0f;
    if (imgbf) {
        const uint4* p = (const uint4*)((const uint16_t*)img + (size_t)plane * HW_);
        for (int i = threadIdx.x; i < HW_ / 8; i += 512) {
            float e[8]; unpack8(p[i], e);
            s += ((e[0] + e[1]) + (e[2] + e[3])) + ((e[4] + e[5]) + (e[6] + e[7]));
        }
    } else {
        const float4* p = (const float4*)((const float*)img + (size_t)plane * HW_);
        for (int i = threadIdx.x; i < HW_ / 4; i += 512) {
            float4 v = p[i];
            s += (v.x + v.y) + (v.z + v.w);
        }
    }

    // wave (64) reduction
    #pragma unroll
    for (int off = 32; off > 0; off >>= 1) s += __shfl_down(s, off, 64);

    __shared__ float wsum[8];
    const int wave = threadIdx.x >> 6;
    if ((threadIdx.x & 63) == 0) wsum[wave] = s;
    __syncthreads();
    if (threadIdx.x == 0) {
        float t = 0.0f;
        #pragma unroll
        for (int i = 0; i < 8; ++i) t += wsum[i];
        means[plane] = t * (1.0f / (float)HW_);
    }
}

// ---------- Pass 2: fused flip/brightness/contrast/saturation/cutout/select ----------
// One thread = 8 consecutive pixels across all 3 channels. 32 blocks of 256
// threads per batch item -> b is block-uniform (no divergence on apply/flip).
// Image re-read rides the L3 (r4 counters: zero extra FETCH); writes are the
// HBM cost. Measured combined kernel time ~30.5 us vs ~30 us traffic floor.
__global__ __launch_bounds__(256) void augment_kernel(
    const void* __restrict__ img,
    const void* __restrict__ apply_u,
    const void* __restrict__ flip_u,
    const void* __restrict__ bri_u,
    const void* __restrict__ con_u,
    const void* __restrict__ sat_u,
    const int*  __restrict__ top_idx,
    const int*  __restrict__ left_idx,
    const float* __restrict__ means,
    const int*  __restrict__ flags,
    void*       __restrict__ out)
{
    const int imgbf = __builtin_amdgcn_readfirstlane(flags[0]);
    const int scbf  = __builtin_amdgcn_readfirstlane(flags[1]);

    const int b   = blockIdx.x >> 5;                          // 32 blocks / batch
    const int rem = ((blockIdx.x & 31) << 8) + threadIdx.x;   // vec idx within batch [0,8192)
    const int h   = rem >> 5;                                 // 32 vecs per row
    const int w0  = (rem & 31) << 3;                          // pixel col base

    const size_t base = (size_t)b * (C_ * HW_) + (size_t)h * W_ + (size_t)w0;

    const bool apply = scal(apply_u, b, scbf) < PROB_;
    if (!apply) {
        // bit-exact passthrough of the original image
        if (imgbf) {
            const uint16_t* ip = (const uint16_t*)img;
            uint16_t*       op = (uint16_t*)out;
            #pragma unroll
            for (int c = 0; c < 3; ++c)
                *(uint4*)(op + base + (size_t)c * HW_) =
                    *(const uint4*)(ip + base + (size_t)c * HW_);
        } else {
            const float* ip = (const float*)img;
            float*       op = (float*)out;
            #pragma unroll
            for (int c = 0; c < 3; ++c) {
                *(float4*)(op + base + (size_t)c * HW_)     = *(const float4*)(ip + base + (size_t)c * HW_);
                *(float4*)(op + base + (size_t)c * HW_ + 4) = *(const float4*)(ip + base + (size_t)c * HW_ + 4);
            }
        }
        return;
    }

    const bool  flip = scal(flip_u, b, scbf) < 0.5f;
    const float fb   = 0.8f + 0.4f * scal(bri_u, b, scbf);
    const float fc   = 0.8f + 0.4f * scal(con_u, b, scbf);
    const float fs   = 0.8f + 0.4f * scal(sat_u, b, scbf);
    const int   t    = top_idx[b];
    const int   l    = left_idx[b];

    // flipped source: output cols [w0, w0+7] <- source cols [255-w0-7 .. 255-w0]
    const int sw = flip ? (W_ - 8 - w0) : w0;
    const size_t sbase = (size_t)b * (C_ * HW_) + (size_t)h * W_ + (size_t)sw;

    float x[3][8];
    #pragma unroll
    for (int c = 0; c < 3; ++c) {
        float e[8];
        if (imgbf) {
            uint4 v = *(const uint4*)((const uint16_t*)img + sbase + (size_t)c * HW_);
            unpack8(v, e);
        } else {
            const float* ip = (const float*)img + sbase + (size_t)c * HW_;
            float4 v0 = *(const float4*)(ip);
            float4 v1 = *(const float4*)(ip + 4);
            e[0] = v0.x; e[1] = v0.y; e[2] = v0.z; e[3] = v0.w;
            e[4] = v1.x; e[5] = v1.y; e[6] = v1.z; e[7] = v1.w;
        }
        // mean after brightness = fb * raw_mean (flip doesn't change the mean)
        const float m = fb * means[b * 3 + c];
        #pragma unroll
        for (int j = 0; j < 8; ++j) {
            const float src = flip ? e[7 - j] : e[j];
            x[c][j] = (src * fb - m) * fc + m;   // brightness + contrast
        }
    }

    // saturation (per-pixel channel mean) + cutout
    const bool row_in = (h >= t) && (h < t + CH_);
    #pragma unroll
    for (int j = 0; j < 8; ++j) {
        const float gray = (x[0][j] + x[1][j] + x[2][j]) * (1.0f / 3.0f);
        const int   w    = w0 + j;
        const bool inside = row_in && (w >= l) && (w < l + CW_);
        #pragma unroll
        for (int c = 0; c < 3; ++c) {
            const float y = (x[c][j] - gray) * fs + gray;
            x[c][j] = inside ? 0.0f : y;
        }
    }

    // pack + store (output dtype follows images dtype)
    if (imgbf) {
        uint16_t* op = (uint16_t*)out;
        #pragma unroll
        for (int c = 0; c < 3; ++c) {
            uint4 ov;
            ov.x = (uint32_t)f2bf(x[c][0]) | ((uint32_t)f2bf(x[c][1]) << 16);
            ov.y = (uint32_t)f2bf(x[c][2]) | ((uint32_t)f2bf(x[c][3]) << 16);
            ov.z = (uint32_t)f2bf(x[c][4]) | ((uint32_t)f2bf(x[c][5]) << 16);
            ov.w = (uint32_t)f2bf(x[c][6]) | ((uint32_t)f2bf(x[c][7]) << 16);
            *(uint4*)(op + base + (size_t)c * HW_) = ov;
        }
    } else {
        float* op = (float*)out;
        #pragma unroll
        for (int c = 0; c < 3; ++c) {
            float4 v0, v1;
            v0.x = x[c][0]; v0.y = x[c][1]; v0.z = x[c][2]; v0.w = x[c][3];
            v1.x = x[c][4]; v1.y = x[c][5]; v1.z = x[c][6]; v1.w = x[c][7];
            *(float4*)(op + base + (size_t)c * HW_)     = v0;
            *(float4*)(op + base + (size_t)c * HW_ + 4) = v1;
        }
    }
}

extern "C" void kernel_launch(void* const* d_in, const int* in_sizes, int n_in,
                              void* d_out, int out_size, void* d_ws, size_t ws_size,
                              hipStream_t stream) {
    const void* img     = d_in[0];
    const void* apply_u = d_in[1];
    const void* flip_u  = d_in[2];
    const void* bri_u   = d_in[3];
    const void* con_u   = d_in[4];
    const void* sat_u   = d_in[5];
    const int*  top_i   = (const int*)d_in[6];
    const int*  left_i  = (const int*)d_in[7];
    float*      means   = (float*)d_ws;                          // 384 floats
    int*        flags   = (int*)((char*)d_ws + NPLANES * sizeof(float)); // 2 ints

    plane_mean_kernel<<<NPLANES, 512, 0, stream>>>(img, apply_u, means, flags);

    const int total_vecs = B_ * HW_ / 8;                         // 1,048,576
    augment_kernel<<<total_vecs / 256, 256, 0, stream>>>(
        img, apply_u, flip_u, bri_u, con_u, sat_u, top_i, left_i, means, flags, d_out);
}